// Round 9
// baseline (283.493 us; speedup 1.0000x reference)
//
#include <hip/hip_runtime.h>
#include <hip/hip_bf16.h>
#include <math.h>

// ---------------------------------------------------------------------------
// TacticalGNN: 3-layer GATv2 (heads mean), global mean pool, linear classify.
// Padded CSR once (64 slots/node). Aggregate: wave/node; the GATHERED operand
// xl is stored bf16 (xlh, 256B/row) halving the compulsory random-gather
// traffic (the measured 55us floor was byte-bound). Lane q owns channels
// q*8..q*8+7 -> ONE uint4 load per edge per 16-lane group; per-head logit
// reduce8 (DPP) aligns with head halves; 4 edge-groups/wave, EPI=8, 3-phase
// mov-free pipeline; no-max softmax (exp2; logits tiny, shift-invariant).
// xr/att/logits/accumulators stay f32.
// ---------------------------------------------------------------------------

#define PAD_SHIFT 6   // 64 slots per node

// ---- padded CSR build: fused histogram + scatter ---------------------------

__global__ void build_csr(const int* __restrict__ edge_src, const int* __restrict__ edge_dst,
                          int* __restrict__ cnt, int* __restrict__ csr, int NE, int E) {
    int e = blockIdx.x * blockDim.x + threadIdx.x;
    if (e >= E) return;
    int s, d;
    if (e < NE) { s = edge_src[e]; d = edge_dst[e]; }
    else        { s = d = e - NE; }
    int pos = atomicAdd(&cnt[d], 1) & 63;     // mask = safety only, never hit
    csr[(d << PAD_SHIFT) + pos] = s;
}

// ---- dense node transform: xlh = bf16(in@Wl+bl), xr = in@Wr+br -------------
// 256-thread blocks: stage NPB=4*NPW rows cooperatively, wave w computes its
// NPW nodes; thread t owns output cols {t, t+64} of both xlh and xr.

template<int IN_CH, int NPW>
__global__ __launch_bounds__(256) void transform_tile(
        const float* __restrict__ in,
        const float* __restrict__ Wl, const float* __restrict__ bl,
        const float* __restrict__ Wr, const float* __restrict__ br,
        ushort* __restrict__ xlh, float* __restrict__ xr, int n) {
    constexpr int NPB = 4 * NPW;
    __shared__ alignas(16) float rows[NPB][IN_CH];
    int tid = threadIdx.x;
    int t = tid & 63, w = tid >> 6;
    int n0 = blockIdx.x * NPB;

    if constexpr (IN_CH % 4 == 0) {
        constexpr int K4 = IN_CH / 4;
        for (int idx = tid; idx < NPB * K4; idx += 256) {
            int nn = idx / K4, k4 = idx - nn * K4;
            int node = n0 + nn; if (node > n - 1) node = n - 1;
            ((float4*)rows[nn])[k4] = ((const float4*)(in + (size_t)node * IN_CH))[k4];
        }
    } else {
        for (int idx = tid; idx < NPB * IN_CH; idx += 256) {
            int nn = idx / IN_CH, k = idx - nn * IN_CH;
            int node = n0 + nn; if (node > n - 1) node = n - 1;
            rows[nn][k] = in[(size_t)node * IN_CH + k];
        }
    }
    __syncthreads();

    int nb = w * NPW;                 // this wave's node slice in LDS
    float accl0[NPW], accl1[NPW], accr0[NPW], accr1[NPW];
    float bl0 = bl[t], bl1 = bl[t + 64], br0 = br[t], br1 = br[t + 64];
#pragma unroll
    for (int nn = 0; nn < NPW; ++nn) {
        accl0[nn] = bl0; accl1[nn] = bl1; accr0[nn] = br0; accr1[nn] = br1;
    }

    if constexpr (IN_CH % 4 == 0) {
        constexpr int K4 = IN_CH / 4;
        for (int k4 = 0; k4 < K4; ++k4) {
            float wl0[4], wl1[4], wr0[4], wr1[4];
#pragma unroll
            for (int j = 0; j < 4; ++j) {
                wl0[j] = Wl[(k4 * 4 + j) * 128 + t];
                wl1[j] = Wl[(k4 * 4 + j) * 128 + t + 64];
                wr0[j] = Wr[(k4 * 4 + j) * 128 + t];
                wr1[j] = Wr[(k4 * 4 + j) * 128 + t + 64];
            }
#pragma unroll
            for (int nn = 0; nn < NPW; ++nn) {
                float4 r = ((const float4*)rows[nb + nn])[k4];
                accl0[nn] = fmaf(r.x, wl0[0], accl0[nn]);
                accl1[nn] = fmaf(r.x, wl1[0], accl1[nn]);
                accr0[nn] = fmaf(r.x, wr0[0], accr0[nn]);
                accr1[nn] = fmaf(r.x, wr1[0], accr1[nn]);
                accl0[nn] = fmaf(r.y, wl0[1], accl0[nn]);
                accl1[nn] = fmaf(r.y, wl1[1], accl1[nn]);
                accr0[nn] = fmaf(r.y, wr0[1], accr0[nn]);
                accr1[nn] = fmaf(r.y, wr1[1], accr1[nn]);
                accl0[nn] = fmaf(r.z, wl0[2], accl0[nn]);
                accl1[nn] = fmaf(r.z, wl1[2], accl1[nn]);
                accr0[nn] = fmaf(r.z, wr0[2], accr0[nn]);
                accr1[nn] = fmaf(r.z, wr1[2], accr1[nn]);
                accl0[nn] = fmaf(r.w, wl0[3], accl0[nn]);
                accl1[nn] = fmaf(r.w, wl1[3], accl1[nn]);
                accr0[nn] = fmaf(r.w, wr0[3], accr0[nn]);
                accr1[nn] = fmaf(r.w, wr1[3], accr1[nn]);
            }
        }
    } else {
#pragma unroll
        for (int k = 0; k < IN_CH; ++k) {
            float wl0 = Wl[k * 128 + t], wl1 = Wl[k * 128 + t + 64];
            float wr0 = Wr[k * 128 + t], wr1 = Wr[k * 128 + t + 64];
#pragma unroll
            for (int nn = 0; nn < NPW; ++nn) {
                float xv = rows[nb + nn][k];
                accl0[nn] = fmaf(xv, wl0, accl0[nn]);
                accl1[nn] = fmaf(xv, wl1, accl1[nn]);
                accr0[nn] = fmaf(xv, wr0, accr0[nn]);
                accr1[nn] = fmaf(xv, wr1, accr1[nn]);
            }
        }
    }

#pragma unroll
    for (int nn = 0; nn < NPW; ++nn) {
        int node = n0 + nb + nn;
        if (node < n) {
            __hip_bfloat16* hl = (__hip_bfloat16*)(xlh + ((size_t)node << 7));
            float* orr = xr + ((size_t)node << 7);
            hl[t]      = __float2bfloat16(accl0[nn]);
            hl[t + 64] = __float2bfloat16(accl1[nn]);
            orr[t] = accr0[nn]; orr[t + 64] = accr1[nn];
        }
    }
}

// ---- DPP reductions ---------------------------------------------------------

template<int CTRL>
__device__ __forceinline__ float dpp_add(float v) {
    int x = __builtin_amdgcn_update_dpp(0, __float_as_int(v), CTRL, 0xF, 0xF, true);
    return v + __int_as_float(x);
}
__device__ __forceinline__ float reduce8(float v) {    // within each 8-lane half
    v = dpp_add<0xB1>(v);   // quad_perm xor 1
    v = dpp_add<0x4E>(v);   // quad_perm xor 2
    v = dpp_add<0x141>(v);  // row_half_mirror (within 8)
    return v;
}
__device__ __forceinline__ float reduce16(float v) {   // within 16-lane row
    v = reduce8(v);
    v = dpp_add<0x140>(v);  // row_mirror (within 16)
    return v;
}

// ---- bf16 x8 unpack (one uint4 = 8 channels) --------------------------------

__device__ __forceinline__ void unpack8(const uint4& u, float c[8]) {
    c[0] = __int_as_float((int)(u.x << 16));
    c[1] = __int_as_float((int)(u.x & 0xffff0000u));
    c[2] = __int_as_float((int)(u.y << 16));
    c[3] = __int_as_float((int)(u.y & 0xffff0000u));
    c[4] = __int_as_float((int)(u.z << 16));
    c[5] = __int_as_float((int)(u.z & 0xffff0000u));
    c[6] = __int_as_float((int)(u.w << 16));
    c[7] = __int_as_float((int)(u.w & 0xffff0000u));
}

// ---- GATv2 aggregation ------------------------------------------------------
// Lane q of each 16-lane group owns channels q*8..q*8+7 of an edge's row
// (TWOHEAD: q<8 -> head0, q>=8 -> head1; reduce8 stays within head halves).
// 4 edge-groups per wave, 2 slots per phase (EPI=8), 3-phase pipeline with
// rows 2 iterations in flight, CSR row register-resident via __shfl.

#define AGG_PH(CUR, FRE)                                                       \
    {                                                                          \
        int tf0 = srcof(it + 2 * EPI + g);                                     \
        int tf1 = srcof(it + 2 * EPI + 4 + g);                                 \
        FRE[0] = *(const uint4*)(xlh + ((size_t)tf0 << 7) + (q << 3));         \
        FRE[1] = *(const uint4*)(xlh + ((size_t)tf1 << 7) + (q << 3));         \
        _Pragma("unroll")                                                      \
        for (int j = 0; j < 2; ++j) {                                          \
            float c[8]; unpack8(CUR[j], c);                                    \
            float p = 0.f;                                                     \
            _Pragma("unroll")                                                  \
            for (int k = 0; k < 8; ++k) {                                      \
                float tt = c[k] + xrv[k];                                      \
                p = fmaf(tt > 0.f ? atv[k] : atw[k], tt, p);                   \
            }                                                                  \
            p = TWOHEAD ? reduce8(p) : reduce16(p);                            \
            float w = (it + j * 4 + g) < deg ? exp2f(p) : 0.f;                 \
            ssum += w;                                                         \
            _Pragma("unroll")                                                  \
            for (int k = 0; k < 8; ++k) acc[k] = fmaf(w, c[k], acc[k]);        \
        }                                                                      \
        it += EPI;                                                             \
    }

template<bool TWOHEAD>
__global__ void gat_agg_fused(const ushort* __restrict__ xlh, const float* __restrict__ xr,
                              const float* __restrict__ att, const float* __restrict__ bias,
                              const int* __restrict__ cnt, const int* __restrict__ csr,
                              float* __restrict__ outbuf, int n) {
    constexpr int EPI = 8;
    constexpr float L2E = 1.4426950408889634f;
    int wid = (blockIdx.x * blockDim.x + threadIdx.x) >> 6;
    if (wid >= n) return;
    int node = wid;
    int lane = threadIdx.x & 63;
    int g = lane >> 4, q = lane & 15;

    // per-lane channels q*8..q*8+7 (f32 side)
    float xrv[8], atv[8], atw[8], acc[8];
    {
        const float4* xp = (const float4*)(xr + ((size_t)node << 7) + q * 8);
        const float4* ap = (const float4*)(att + q * 8);
        float4 x0 = xp[0], x1 = xp[1], a0 = ap[0], a1 = ap[1];
        xrv[0]=x0.x; xrv[1]=x0.y; xrv[2]=x0.z; xrv[3]=x0.w;
        xrv[4]=x1.x; xrv[5]=x1.y; xrv[6]=x1.z; xrv[7]=x1.w;
        atv[0]=a0.x*L2E; atv[1]=a0.y*L2E; atv[2]=a0.z*L2E; atv[3]=a0.w*L2E;
        atv[4]=a1.x*L2E; atv[5]=a1.y*L2E; atv[6]=a1.z*L2E; atv[7]=a1.w*L2E;
#pragma unroll
        for (int k = 0; k < 8; ++k) { atw[k] = 0.2f * atv[k]; acc[k] = 0.f; }
    }

    int deg = cnt[node]; if (deg > 64) deg = 64;   // >= 1 (self-loop)
    int idxvec = csr[((size_t)node << PAD_SHIFT) + lane];   // whole CSR row
    auto srcof = [&](int p) { return __shfl(idxvec, p < deg ? p : 0, 64); };

    // prologue: rows for iters 0 (X) and 1 (Y) in flight
    uint4 X[2], Y[2], Z[2];
    {
        int s00 = srcof(g), s01 = srcof(4 + g);
        int s10 = srcof(EPI + g), s11 = srcof(EPI + 4 + g);
        X[0] = *(const uint4*)(xlh + ((size_t)s00 << 7) + (q << 3));
        X[1] = *(const uint4*)(xlh + ((size_t)s01 << 7) + (q << 3));
        Y[0] = *(const uint4*)(xlh + ((size_t)s10 << 7) + (q << 3));
        Y[1] = *(const uint4*)(xlh + ((size_t)s11 << 7) + (q << 3));
    }

    float ssum = 0.f;
    int it = 0;
    while (true) {
        AGG_PH(X, Z)
        if (it >= deg) break;
        AGG_PH(Y, X)
        if (it >= deg) break;
        AGG_PH(Z, Y)
        if (it >= deg) break;
    }

    // merge the 4 edge-groups (lane bits 4,5): pure sums
    ssum += __shfl_xor(ssum, 32, 64);
    ssum += __shfl_xor(ssum, 16, 64);
#pragma unroll
    for (int k = 0; k < 8; ++k) {
        acc[k] += __shfl_xor(acc[k], 32, 64);
        acc[k] += __shfl_xor(acc[k], 16, 64);
    }

    float inv = 1.f / ssum;
    if constexpr (TWOHEAD) {
        float o[8];
#pragma unroll
        for (int k = 0; k < 8; ++k) {
            float r = acc[k] * inv;
            float ro = __shfl_xor(r, 8, 64);          // other head, same channel
            float v = 0.5f * (r + ro) + bias[(q & 7) * 8 + k];
            o[k] = (v > 0.f) ? v : expm1f(v);         // ELU
        }
        if (lane < 8) {
            float4* op = (float4*)(outbuf + (size_t)node * 64 + q * 8);
            op[0] = make_float4(o[0], o[1], o[2], o[3]);
            op[1] = make_float4(o[4], o[5], o[6], o[7]);
        }
    } else {
        float o[8];
#pragma unroll
        for (int k = 0; k < 8; ++k) o[k] = acc[k] * inv + bias[q * 8 + k];
        if (lane < 16) {
            float4* op = (float4*)(outbuf + ((size_t)node << 7) + q * 8);
            op[0] = make_float4(o[0], o[1], o[2], o[3]);
            op[1] = make_float4(o[4], o[5], o[6], o[7]);
        }
    }
}

// ---- global mean pool (batch sorted) + classify ----------------------------

__device__ __forceinline__ int lower_bound(const int* __restrict__ a, int n, int key) {
    int lo = 0, hi = n;
    while (lo < hi) {
        int mid = (lo + hi) >> 1;
        if (a[mid] < key) lo = mid + 1; else hi = mid;
    }
    return lo;
}

__global__ void pool_kernel(const float* __restrict__ h3, const int* __restrict__ batch,
                            const float* __restrict__ Wc, const float* __restrict__ bc,
                            float* __restrict__ out, int n, int G) {
    int g = blockIdx.x;
    int tid = threadIdx.x;   // 0..127
    __shared__ float mean[128];
    int start = lower_bound(batch, n, g);
    int end   = lower_bound(batch, n, g + 1);
    float s0 = 0.f, s1 = 0.f, s2 = 0.f, s3 = 0.f;
    int node = start;
    for (; node + 3 < end; node += 4) {
        s0 += h3[(size_t)node * 128 + tid];
        s1 += h3[(size_t)(node + 1) * 128 + tid];
        s2 += h3[(size_t)(node + 2) * 128 + tid];
        s3 += h3[(size_t)(node + 3) * 128 + tid];
    }
    for (; node < end; ++node) s0 += h3[(size_t)node * 128 + tid];
    float s = (s0 + s1) + (s2 + s3);
    int cnt = end - start;
    float mv = s / (float)(cnt > 0 ? cnt : 1);
    mean[tid] = mv;
    __syncthreads();
    if (tid < 11) {
        float o = bc[tid];
        for (int c = 0; c < 128; ++c) o += mean[c] * Wc[c * 11 + tid];
        out[g * 11 + tid] = o;
    }
}

// ---------------------------------------------------------------------------

extern "C" void kernel_launch(void* const* d_in, const int* in_sizes, int n_in,
                              void* d_out, int out_size, void* d_ws, size_t ws_size,
                              hipStream_t stream) {
    const float* x     = (const float*)d_in[0];
    const int*   ei    = (const int*)d_in[1];
    const int*   batch = (const int*)d_in[2];
    const float* W1l = (const float*)d_in[3],  *b1l = (const float*)d_in[4];
    const float* W1r = (const float*)d_in[5],  *b1r = (const float*)d_in[6];
    const float* att1 = (const float*)d_in[7], *bias1 = (const float*)d_in[8];
    const float* W2l = (const float*)d_in[9],  *b2l = (const float*)d_in[10];
    const float* W2r = (const float*)d_in[11], *b2r = (const float*)d_in[12];
    const float* att2 = (const float*)d_in[13], *bias2 = (const float*)d_in[14];
    const float* W3l = (const float*)d_in[15], *b3l = (const float*)d_in[16];
    const float* W3r = (const float*)d_in[17], *b3r = (const float*)d_in[18];
    const float* att3 = (const float*)d_in[19], *bias3 = (const float*)d_in[20];
    const float* Wc  = (const float*)d_in[21], *bc  = (const float*)d_in[22];
    float* out = (float*)d_out;

    const int N  = in_sizes[0] / 7;      // 50000
    const int NE = in_sizes[1] / 2;      // 600000
    const int E  = NE + N;               // + self loops
    const int G  = out_size / 11;        // 512

    const int* edge_src = ei;
    const int* edge_dst = ei + NE;

    // workspace carve-out (256B aligned segments)
    char* p = (char*)d_ws;
    auto alloc = [&](size_t bytes) { void* r = (void*)p; p += (bytes + 255) & ~(size_t)255; return r; };
    int*    cnt  = (int*)alloc((size_t)N * sizeof(int));
    int*    csr  = (int*)alloc((size_t)N * 64 * sizeof(int));
    ushort* xlh  = (ushort*)alloc((size_t)N * 128 * sizeof(ushort));
    float*  xr   = (float*)alloc((size_t)N * 128 * sizeof(float));
    float*  hbuf = (float*)alloc((size_t)N * 128 * sizeof(float));

    // ---- padded CSR build (edge set identical across layers) ----
    (void)hipMemsetAsync(cnt, 0, (size_t)N * sizeof(int), stream);
    build_csr<<<(E + 255) / 256, 256, 0, stream>>>(edge_src, edge_dst, cnt, csr, NE, E);

    const int NPB = 32;                  // 4 waves x 8 nodes
    int tgrid = (N + NPB - 1) / NPB;
    int agrid = (N + 3) / 4;             // 4 waves (nodes) per 256-thread block

    // ---- layer 1: 7 -> (2,64), head-mean+bias+ELU fused ----
    transform_tile<7, 8><<<tgrid, 256, 0, stream>>>(x, W1l, b1l, W1r, b1r, xlh, xr, N);
    gat_agg_fused<true><<<agrid, 256, 0, stream>>>(xlh, xr, att1, bias1, cnt, csr, hbuf, N);

    // ---- layer 2: 64 -> (2,64), head-mean+bias+ELU fused ----
    transform_tile<64, 8><<<tgrid, 256, 0, stream>>>(hbuf, W2l, b2l, W2r, b2r, xlh, xr, N);
    gat_agg_fused<true><<<agrid, 256, 0, stream>>>(xlh, xr, att2, bias2, cnt, csr, hbuf, N);

    // ---- layer 3: 64 -> (1,128), +bias, no act ----
    transform_tile<64, 8><<<tgrid, 256, 0, stream>>>(hbuf, W3l, b3l, W3r, b3r, xlh, xr, N);
    gat_agg_fused<false><<<agrid, 256, 0, stream>>>(xlh, xr, att3, bias3, cnt, csr, hbuf, N);

    // ---- pool + classify ----
    pool_kernel<<<G, 128, 0, stream>>>(hbuf, batch, Wc, bc, out, N, G);
}

// Round 10
// 248.392 us; speedup vs baseline: 1.1413x; 1.1413x over previous
//
#include <hip/hip_runtime.h>
#include <hip/hip_bf16.h>
#include <math.h>

// ---------------------------------------------------------------------------
// TacticalGNN: 3-layer GATv2 (heads mean), global mean pool, linear classify.
// Padded CSR once (64 slots/node). Aggregate: wave/node; gathered operand xl
// stored bf16 (halves compulsory random-gather traffic, R9: FETCH 161->83MB)
// BUT with R8's lane geometry (16-lane group per edge-head, 4 ch/lane, uint2
// loads + unpack4) whose VALU cost measured ~27us busy vs R9's 50us.
// 3-phase mov-free pipeline, rows 2 iters in flight, CSR row in registers via
// __shfl, no-max softmax (exp2; logits tiny, shift-invariant).
// ---------------------------------------------------------------------------

#define PAD_SHIFT 6   // 64 slots per node

// ---- padded CSR build: fused histogram + scatter ---------------------------

__global__ void build_csr(const int* __restrict__ edge_src, const int* __restrict__ edge_dst,
                          int* __restrict__ cnt, int* __restrict__ csr, int NE, int E) {
    int e = blockIdx.x * blockDim.x + threadIdx.x;
    if (e >= E) return;
    int s, d;
    if (e < NE) { s = edge_src[e]; d = edge_dst[e]; }
    else        { s = d = e - NE; }
    int pos = atomicAdd(&cnt[d], 1) & 63;     // mask = safety only, never hit
    csr[(d << PAD_SHIFT) + pos] = s;
}

// ---- dense node transform: xlh = bf16(in@Wl+bl), xr = in@Wr+br -------------
// 256-thread blocks: stage NPB=4*NPW rows cooperatively, wave w computes its
// NPW nodes; thread t owns output cols {t, t+64} of both xlh and xr.

template<int IN_CH, int NPW>
__global__ __launch_bounds__(256) void transform_tile(
        const float* __restrict__ in,
        const float* __restrict__ Wl, const float* __restrict__ bl,
        const float* __restrict__ Wr, const float* __restrict__ br,
        ushort* __restrict__ xlh, float* __restrict__ xr, int n) {
    constexpr int NPB = 4 * NPW;
    __shared__ alignas(16) float rows[NPB][IN_CH];
    int tid = threadIdx.x;
    int t = tid & 63, w = tid >> 6;
    int n0 = blockIdx.x * NPB;

    if constexpr (IN_CH % 4 == 0) {
        constexpr int K4 = IN_CH / 4;
        for (int idx = tid; idx < NPB * K4; idx += 256) {
            int nn = idx / K4, k4 = idx - nn * K4;
            int node = n0 + nn; if (node > n - 1) node = n - 1;
            ((float4*)rows[nn])[k4] = ((const float4*)(in + (size_t)node * IN_CH))[k4];
        }
    } else {
        for (int idx = tid; idx < NPB * IN_CH; idx += 256) {
            int nn = idx / IN_CH, k = idx - nn * IN_CH;
            int node = n0 + nn; if (node > n - 1) node = n - 1;
            rows[nn][k] = in[(size_t)node * IN_CH + k];
        }
    }
    __syncthreads();

    int nb = w * NPW;                 // this wave's node slice in LDS
    float accl0[NPW], accl1[NPW], accr0[NPW], accr1[NPW];
    float bl0 = bl[t], bl1 = bl[t + 64], br0 = br[t], br1 = br[t + 64];
#pragma unroll
    for (int nn = 0; nn < NPW; ++nn) {
        accl0[nn] = bl0; accl1[nn] = bl1; accr0[nn] = br0; accr1[nn] = br1;
    }

    if constexpr (IN_CH % 4 == 0) {
        constexpr int K4 = IN_CH / 4;
        for (int k4 = 0; k4 < K4; ++k4) {
            float wl0[4], wl1[4], wr0[4], wr1[4];
#pragma unroll
            for (int j = 0; j < 4; ++j) {
                wl0[j] = Wl[(k4 * 4 + j) * 128 + t];
                wl1[j] = Wl[(k4 * 4 + j) * 128 + t + 64];
                wr0[j] = Wr[(k4 * 4 + j) * 128 + t];
                wr1[j] = Wr[(k4 * 4 + j) * 128 + t + 64];
            }
#pragma unroll
            for (int nn = 0; nn < NPW; ++nn) {
                float4 r = ((const float4*)rows[nb + nn])[k4];
                accl0[nn] = fmaf(r.x, wl0[0], accl0[nn]);
                accl1[nn] = fmaf(r.x, wl1[0], accl1[nn]);
                accr0[nn] = fmaf(r.x, wr0[0], accr0[nn]);
                accr1[nn] = fmaf(r.x, wr1[0], accr1[nn]);
                accl0[nn] = fmaf(r.y, wl0[1], accl0[nn]);
                accl1[nn] = fmaf(r.y, wl1[1], accl1[nn]);
                accr0[nn] = fmaf(r.y, wr0[1], accr0[nn]);
                accr1[nn] = fmaf(r.y, wr1[1], accr1[nn]);
                accl0[nn] = fmaf(r.z, wl0[2], accl0[nn]);
                accl1[nn] = fmaf(r.z, wl1[2], accl1[nn]);
                accr0[nn] = fmaf(r.z, wr0[2], accr0[nn]);
                accr1[nn] = fmaf(r.z, wr1[2], accr1[nn]);
                accl0[nn] = fmaf(r.w, wl0[3], accl0[nn]);
                accl1[nn] = fmaf(r.w, wl1[3], accl1[nn]);
                accr0[nn] = fmaf(r.w, wr0[3], accr0[nn]);
                accr1[nn] = fmaf(r.w, wr1[3], accr1[nn]);
            }
        }
    } else {
#pragma unroll
        for (int k = 0; k < IN_CH; ++k) {
            float wl0 = Wl[k * 128 + t], wl1 = Wl[k * 128 + t + 64];
            float wr0 = Wr[k * 128 + t], wr1 = Wr[k * 128 + t + 64];
#pragma unroll
            for (int nn = 0; nn < NPW; ++nn) {
                float xv = rows[nb + nn][k];
                accl0[nn] = fmaf(xv, wl0, accl0[nn]);
                accl1[nn] = fmaf(xv, wl1, accl1[nn]);
                accr0[nn] = fmaf(xv, wr0, accr0[nn]);
                accr1[nn] = fmaf(xv, wr1, accr1[nn]);
            }
        }
    }

#pragma unroll
    for (int nn = 0; nn < NPW; ++nn) {
        int node = n0 + nb + nn;
        if (node < n) {
            __hip_bfloat16* hl = (__hip_bfloat16*)(xlh + ((size_t)node << 7));
            float* orr = xr + ((size_t)node << 7);
            hl[t]      = __float2bfloat16(accl0[nn]);
            hl[t + 64] = __float2bfloat16(accl1[nn]);
            orr[t] = accr0[nn]; orr[t + 64] = accr1[nn];
        }
    }
}

// ---- DPP reductions ---------------------------------------------------------

template<int CTRL>
__device__ __forceinline__ float dpp_add(float v) {
    int x = __builtin_amdgcn_update_dpp(0, __float_as_int(v), CTRL, 0xF, 0xF, true);
    return v + __int_as_float(x);
}
__device__ __forceinline__ float reduce16(float v) {   // within 16-lane row
    v = dpp_add<0xB1>(v);   // quad_perm xor 1
    v = dpp_add<0x4E>(v);   // quad_perm xor 2
    v = dpp_add<0x141>(v);  // row_half_mirror
    v = dpp_add<0x140>(v);  // row_mirror
    return v;
}

// ---- bf16 x4 unpack (one uint2 = 4 channels) --------------------------------

__device__ __forceinline__ void unpack4(const uint2& u, float c[4]) {
    c[0] = __int_as_float((int)(u.x << 16));
    c[1] = __int_as_float((int)(u.x & 0xffff0000u));
    c[2] = __int_as_float((int)(u.y << 16));
    c[3] = __int_as_float((int)(u.y & 0xffff0000u));
}

// ---- GATv2 aggregation helpers ---------------------------------------------

__device__ __forceinline__ float chan4v(float p, const float c[4], const float xv[4],
                                        const float a[4], const float a2[4]) {
#pragma unroll
    for (int k = 0; k < 4; ++k) {
        float t = c[k] + xv[k];
        p = fmaf(t > 0.f ? a[k] : a2[k], t, p);
    }
    return p;
}
__device__ __forceinline__ void acc4v(float acc[4], float w, const float c[4]) {
#pragma unroll
    for (int k = 0; k < 4; ++k) acc[k] = fmaf(w, c[k], acc[k]);
}

// ---- GATv2 aggregation ------------------------------------------------------
// TWOHEAD (C=64,H=2): 4 groups = 2 edge-slots x 2 heads; lane q owns 4 chans
// of its head (uint2 load). !TWOHEAD (C=128,H=1): 4 edge-groups x 2 slots;
// lane q owns chans q*4 and q*4+64 (2 uint2 loads). 3-phase pipeline, rows 2
// iters in flight, CSR row register-resident via __shfl.

#define AGG_PH(CUR0, CUR1, FRE0, FRE1)                                         \
    {                                                                          \
        int tf0 = srcof(it + 2 * EPI + eg);                                    \
        int tf1 = srcof(it + 2 * EPI + STEP + eg);                             \
        FRE0[0] = *(const uint2*)(xlh + ((size_t)tf0 << 7) + rowo);            \
        FRE0[1] = *(const uint2*)(xlh + ((size_t)tf1 << 7) + rowo);            \
        if constexpr (!TWOHEAD) {                                              \
            FRE1[0] = *(const uint2*)(xlh + ((size_t)tf0 << 7) + rowo + 64);   \
            FRE1[1] = *(const uint2*)(xlh + ((size_t)tf1 << 7) + rowo + 64);   \
        }                                                                      \
        bool v0 = (it + eg) < deg, v1 = (it + STEP + eg) < deg;                \
        float ca[4], cb[4], da[4], db[4];                                      \
        unpack4(CUR0[0], ca); unpack4(CUR0[1], cb);                            \
        float pa = chan4v(0.f, ca, xrv0, atv0, atw0);                          \
        float pb = chan4v(0.f, cb, xrv0, atv0, atw0);                          \
        if constexpr (!TWOHEAD) {                                              \
            unpack4(CUR1[0], da); unpack4(CUR1[1], db);                        \
            pa = chan4v(pa, da, xrv1, atv1, atw1);                             \
            pb = chan4v(pb, db, xrv1, atv1, atw1);                             \
        }                                                                      \
        pa = reduce16(pa); pb = reduce16(pb);                                  \
        float w0 = v0 ? exp2f(pa) : 0.f;                                       \
        float w1 = v1 ? exp2f(pb) : 0.f;                                       \
        ssum += w0 + w1;                                                       \
        acc4v(acc0, w0, ca); acc4v(acc0, w1, cb);                              \
        if constexpr (!TWOHEAD) { acc4v(acc1, w0, da); acc4v(acc1, w1, db); }  \
        it += EPI;                                                             \
    }

template<bool TWOHEAD>
__global__ void gat_agg_fused(const ushort* __restrict__ xlh, const float* __restrict__ xr,
                              const float* __restrict__ att, const float* __restrict__ bias,
                              const int* __restrict__ cnt, const int* __restrict__ csr,
                              float* __restrict__ outbuf, int n) {
    constexpr int STEP = TWOHEAD ? 2 : 4;
    constexpr int EPI  = 2 * STEP;
    constexpr float L2E = 1.4426950408889634f;
    int wid = (blockIdx.x * blockDim.x + threadIdx.x) >> 6;
    if (wid >= n) return;
    int node = wid;
    int lane = threadIdx.x & 63;
    int g = lane >> 4, q = lane & 15;
    int eg   = TWOHEAD ? (g >> 1) : g;
    int head = TWOHEAD ? (g & 1)  : 0;
    int rowo = TWOHEAD ? (head * 64 + q * 4) : (q * 4);   // element offset

    float xrv0[4], atv0[4], atw0[4], acc0[4];
    float xrv1[4], atv1[4], atw1[4], acc1[4];
    {
        float4 x0 = *(const float4*)(xr + ((size_t)node << 7) + rowo);
        float4 a0 = *(const float4*)(att + rowo);
        xrv0[0]=x0.x; xrv0[1]=x0.y; xrv0[2]=x0.z; xrv0[3]=x0.w;
        atv0[0]=a0.x*L2E; atv0[1]=a0.y*L2E; atv0[2]=a0.z*L2E; atv0[3]=a0.w*L2E;
#pragma unroll
        for (int k = 0; k < 4; ++k) { atw0[k] = 0.2f * atv0[k]; acc0[k] = 0.f; }
        if constexpr (!TWOHEAD) {
            float4 x1 = *(const float4*)(xr + ((size_t)node << 7) + rowo + 64);
            float4 a1 = *(const float4*)(att + rowo + 64);
            xrv1[0]=x1.x; xrv1[1]=x1.y; xrv1[2]=x1.z; xrv1[3]=x1.w;
            atv1[0]=a1.x*L2E; atv1[1]=a1.y*L2E; atv1[2]=a1.z*L2E; atv1[3]=a1.w*L2E;
#pragma unroll
            for (int k = 0; k < 4; ++k) { atw1[k] = 0.2f * atv1[k]; acc1[k] = 0.f; }
        }
    }

    int deg = cnt[node]; if (deg > 64) deg = 64;   // >= 1 (self-loop)
    int idxvec = csr[((size_t)node << PAD_SHIFT) + lane];   // whole CSR row
    auto srcof = [&](int p) { return __shfl(idxvec, p < deg ? p : 0, 64); };

    // prologue: rows for iters 0 (X) and 1 (Y) in flight
    uint2 X0[2], X1[2], Y0[2], Y1[2], Z0[2], Z1[2];
    {
        int s00 = srcof(eg), s01 = srcof(STEP + eg);
        int s10 = srcof(EPI + eg), s11 = srcof(EPI + STEP + eg);
        X0[0] = *(const uint2*)(xlh + ((size_t)s00 << 7) + rowo);
        X0[1] = *(const uint2*)(xlh + ((size_t)s01 << 7) + rowo);
        Y0[0] = *(const uint2*)(xlh + ((size_t)s10 << 7) + rowo);
        Y0[1] = *(const uint2*)(xlh + ((size_t)s11 << 7) + rowo);
        if constexpr (!TWOHEAD) {
            X1[0] = *(const uint2*)(xlh + ((size_t)s00 << 7) + rowo + 64);
            X1[1] = *(const uint2*)(xlh + ((size_t)s01 << 7) + rowo + 64);
            Y1[0] = *(const uint2*)(xlh + ((size_t)s10 << 7) + rowo + 64);
            Y1[1] = *(const uint2*)(xlh + ((size_t)s11 << 7) + rowo + 64);
        }
    }

    float ssum = 0.f;
    int it = 0;
    while (true) {
        AGG_PH(X0, X1, Z0, Z1)
        if (it >= deg) break;
        AGG_PH(Y0, Y1, X0, X1)
        if (it >= deg) break;
        AGG_PH(Z0, Z1, Y0, Y1)
        if (it >= deg) break;
    }

    // merge edge-slot groups (pure sums): xor 32; then (!TWOHEAD) xor 16 too
    ssum += __shfl_xor(ssum, 32, 64);
#pragma unroll
    for (int k = 0; k < 4; ++k) acc0[k] += __shfl_xor(acc0[k], 32, 64);
    if constexpr (!TWOHEAD) {
        ssum += __shfl_xor(ssum, 16, 64);
#pragma unroll
        for (int k = 0; k < 4; ++k) {
            acc1[k] += __shfl_xor(acc1[k], 32, 64);
            acc0[k] += __shfl_xor(acc0[k], 16, 64);
            acc1[k] += __shfl_xor(acc1[k], 16, 64);
        }
    }

    float inv = 1.f / ssum;
    if constexpr (TWOHEAD) {
        float o[4];
#pragma unroll
        for (int k = 0; k < 4; ++k) {
            float r = acc0[k] * inv;
            float ro = __shfl_xor(r, 16, 64);         // other head, same channel
            float v = 0.5f * (r + ro) + bias[q * 4 + k];
            o[k] = (v > 0.f) ? v : expm1f(v);         // ELU
        }
        if (lane < 16)
            ((float4*)(outbuf + (size_t)node * 64))[q] = make_float4(o[0], o[1], o[2], o[3]);
    } else {
        float o0[4], o1[4];
#pragma unroll
        for (int k = 0; k < 4; ++k) {
            o0[k] = acc0[k] * inv + bias[q * 4 + k];
            o1[k] = acc1[k] * inv + bias[q * 4 + 64 + k];
        }
        if (lane < 16) {
            float4* op = (float4*)(outbuf + ((size_t)node << 7));
            op[q]      = make_float4(o0[0], o0[1], o0[2], o0[3]);
            op[q + 16] = make_float4(o1[0], o1[1], o1[2], o1[3]);
        }
    }
}

// ---- global mean pool (batch sorted) + classify ----------------------------

__device__ __forceinline__ int lower_bound(const int* __restrict__ a, int n, int key) {
    int lo = 0, hi = n;
    while (lo < hi) {
        int mid = (lo + hi) >> 1;
        if (a[mid] < key) lo = mid + 1; else hi = mid;
    }
    return lo;
}

__global__ void pool_kernel(const float* __restrict__ h3, const int* __restrict__ batch,
                            const float* __restrict__ Wc, const float* __restrict__ bc,
                            float* __restrict__ out, int n, int G) {
    int g = blockIdx.x;
    int tid = threadIdx.x;   // 0..127
    __shared__ float mean[128];
    int start = lower_bound(batch, n, g);
    int end   = lower_bound(batch, n, g + 1);
    float s0 = 0.f, s1 = 0.f, s2 = 0.f, s3 = 0.f;
    int node = start;
    for (; node + 3 < end; node += 4) {
        s0 += h3[(size_t)node * 128 + tid];
        s1 += h3[(size_t)(node + 1) * 128 + tid];
        s2 += h3[(size_t)(node + 2) * 128 + tid];
        s3 += h3[(size_t)(node + 3) * 128 + tid];
    }
    for (; node < end; ++node) s0 += h3[(size_t)node * 128 + tid];
    float s = (s0 + s1) + (s2 + s3);
    int cnt = end - start;
    float mv = s / (float)(cnt > 0 ? cnt : 1);
    mean[tid] = mv;
    __syncthreads();
    if (tid < 11) {
        float o = bc[tid];
        for (int c = 0; c < 128; ++c) o += mean[c] * Wc[c * 11 + tid];
        out[g * 11 + tid] = o;
    }
}

// ---------------------------------------------------------------------------

extern "C" void kernel_launch(void* const* d_in, const int* in_sizes, int n_in,
                              void* d_out, int out_size, void* d_ws, size_t ws_size,
                              hipStream_t stream) {
    const float* x     = (const float*)d_in[0];
    const int*   ei    = (const int*)d_in[1];
    const int*   batch = (const int*)d_in[2];
    const float* W1l = (const float*)d_in[3],  *b1l = (const float*)d_in[4];
    const float* W1r = (const float*)d_in[5],  *b1r = (const float*)d_in[6];
    const float* att1 = (const float*)d_in[7], *bias1 = (const float*)d_in[8];
    const float* W2l = (const float*)d_in[9],  *b2l = (const float*)d_in[10];
    const float* W2r = (const float*)d_in[11], *b2r = (const float*)d_in[12];
    const float* att2 = (const float*)d_in[13], *bias2 = (const float*)d_in[14];
    const float* W3l = (const float*)d_in[15], *b3l = (const float*)d_in[16];
    const float* W3r = (const float*)d_in[17], *b3r = (const float*)d_in[18];
    const float* att3 = (const float*)d_in[19], *bias3 = (const float*)d_in[20];
    const float* Wc  = (const float*)d_in[21], *bc  = (const float*)d_in[22];
    float* out = (float*)d_out;

    const int N  = in_sizes[0] / 7;      // 50000
    const int NE = in_sizes[1] / 2;      // 600000
    const int E  = NE + N;               // + self loops
    const int G  = out_size / 11;        // 512

    const int* edge_src = ei;
    const int* edge_dst = ei + NE;

    // workspace carve-out (256B aligned segments)
    char* p = (char*)d_ws;
    auto alloc = [&](size_t bytes) { void* r = (void*)p; p += (bytes + 255) & ~(size_t)255; return r; };
    int*    cnt  = (int*)alloc((size_t)N * sizeof(int));
    int*    csr  = (int*)alloc((size_t)N * 64 * sizeof(int));
    ushort* xlh  = (ushort*)alloc((size_t)N * 128 * sizeof(ushort));
    float*  xr   = (float*)alloc((size_t)N * 128 * sizeof(float));
    float*  hbuf = (float*)alloc((size_t)N * 128 * sizeof(float));

    // ---- padded CSR build (edge set identical across layers) ----
    (void)hipMemsetAsync(cnt, 0, (size_t)N * sizeof(int), stream);
    build_csr<<<(E + 255) / 256, 256, 0, stream>>>(edge_src, edge_dst, cnt, csr, NE, E);

    const int NPB = 32;                  // 4 waves x 8 nodes
    int tgrid = (N + NPB - 1) / NPB;
    int agrid = (N + 3) / 4;             // 4 waves (nodes) per 256-thread block

    // ---- layer 1: 7 -> (2,64), head-mean+bias+ELU fused ----
    transform_tile<7, 8><<<tgrid, 256, 0, stream>>>(x, W1l, b1l, W1r, b1r, xlh, xr, N);
    gat_agg_fused<true><<<agrid, 256, 0, stream>>>(xlh, xr, att1, bias1, cnt, csr, hbuf, N);

    // ---- layer 2: 64 -> (2,64), head-mean+bias+ELU fused ----
    transform_tile<64, 8><<<tgrid, 256, 0, stream>>>(hbuf, W2l, b2l, W2r, b2r, xlh, xr, N);
    gat_agg_fused<true><<<agrid, 256, 0, stream>>>(xlh, xr, att2, bias2, cnt, csr, hbuf, N);

    // ---- layer 3: 64 -> (1,128), +bias, no act ----
    transform_tile<64, 8><<<tgrid, 256, 0, stream>>>(hbuf, W3l, b3l, W3r, b3r, xlh, xr, N);
    gat_agg_fused<false><<<agrid, 256, 0, stream>>>(xlh, xr, att3, bias3, cnt, csr, hbuf, N);

    // ---- pool + classify ----
    pool_kernel<<<G, 128, 0, stream>>>(hbuf, batch, Wc, bc, out, N, G);
}